// Round 3
// baseline (17883.757 us; speedup 1.0000x reference)
//
#include <hip/hip_runtime.h>
#include <stdint.h>

// SequenceDecoder: B=128, EMB=512, H=1024, V=8192, T=100 (99 sequential steps).
//  - argmax(log_softmax) == argmax(raw): recurrence needs only raw-logit argmax.
//  - fp16 hi/lo split GEMMs (3 MFMA passes, lo x2048) ~22 mantissa bits.
//  - Weights pre-converted ONCE to fp16 hi|lo tile images with the LDS
//    XOR-swizzle (chunk ^= row&7) baked in. All K-loop staging is
//    global_load_lds width-16 DMA. Triple-buffered LDS, counted vmcnt.
//  - NEW: single PERSISTENT kernel runs all 99 steps (256 WGs == 256 CUs,
//    96KB LDS forces 1 WG/CU -> provable co-residency). Two 2-level grid
//    barriers per step replace the 198 kernel launches (launch-gap theory).
//  - GRU fused via split-K ticket (winner of 4 q-WGs per cg does GRU + emits
//    swizzled fp16 h tile).

#define Bb   128
#define EMBd 512
#define Hd   1024
#define Vd   8192
#define Td   100
#define NWG  256

typedef __attribute__((ext_vector_type(8))) _Float16 half8;
typedef __attribute__((ext_vector_type(4))) float f32x4;
typedef unsigned long long ull;

#define LOSCALE 2048.0f
#define LOINV   (1.0f/2048.0f)

__device__ __forceinline__ uint32_t fkey(float f) {
  uint32_t u = __float_as_uint(f);
  return (u & 0x80000000u) ? ~u : (u | 0x80000000u);
}
__device__ __forceinline__ ull umax64(ull a, ull b) { return a > b ? a : b; }

__device__ __forceinline__ void dma16(const void* g, void* l) {
  __builtin_amdgcn_global_load_lds((const uint32_t*)g, (uint32_t*)l, 16, 0, 0);
}

// split 8 fp32 into fp16 hi + (lo*2048)
__device__ __forceinline__ void cvt8(const float4 v0, const float4 v1,
                                     half8& hh, half8& ll) {
  float vv[8] = {v0.x, v0.y, v0.z, v0.w, v1.x, v1.y, v1.z, v1.w};
#pragma unroll
  for (int i = 0; i < 8; ++i) {
    _Float16 h = (_Float16)vv[i];
    hh[i] = h;
    ll[i] = (_Float16)((vv[i] - (float)h) * LOSCALE);
  }
}

// ---------------------------------------------------------------- init
__global__ void k_init(const float* __restrict__ x, float* __restrict__ hbuf0,
                       ull* __restrict__ amax, int* __restrict__ ticket,
                       char* __restrict__ hpre0, uint32_t* __restrict__ bar) {
  int tid = blockIdx.x * 256 + threadIdx.x;
  if (tid < Bb * Hd) hbuf0[tid] = x[tid];
  if (tid < Td * Bb) amax[tid] = (tid < Bb) ? 0xFFFFFFFFull : 0ull;  // t=0: idx=0
  if (tid < 64) ticket[tid] = 0;
  if (tid >= 64 && tid < 64 + 256) bar[tid - 64] = 0;
  if (tid < 16384) {
    int b = tid & 127, sc = tid >> 7;
    int st = sc >> 2, c = sc & 3;
    const float* src = x + b * Hd + st * 32 + c * 8;
    float4 v0 = *(const float4*)src, v1 = *(const float4*)(src + 4);
    half8 hh, ll; cvt8(v0, v1, hh, ll);
    char* hp = hpre0 + st * 16384 + b * 128;
    *(half8*)(hp + ((c       ^ (b & 7))) * 16) = hh;
    *(half8*)(hp + (((c + 4) ^ (b & 7))) * 16) = ll;
  }
}

// ------------------------------------------------------------- prep kernels
// emb_pre: [row 8192][st_e 16][chunk 8][16B], UNSWIZZLED (swizzle applied via
// per-lane DMA source index at gather time, since LDS row = batch, not emb row)
__global__ void k_prep_emb(const float* __restrict__ emb, char* __restrict__ embp) {
  int t = blockIdx.x * 256 + threadIdx.x;          // 524288 total
  int row = t >> 6, rem = t & 63, st = rem >> 2, c = rem & 3;
  const float* src = emb + (size_t)row * EMBd + st * 32 + c * 8;
  float4 v0 = *(const float4*)src, v1 = *(const float4*)(src + 4);
  half8 hh, ll; cvt8(v0, v1, hh, ll);
  char* d = embp + (size_t)row * 2048 + st * 128;
  *(half8*)(d + c * 16) = hh;
  *(half8*)(d + (c + 4) * 16) = ll;
}

// wpre: per (cg,q,st) tile: [48 rows][128B], swizzled (chunk ^= r&7)
__global__ void k_prep_w(const float* __restrict__ w_ih, const float* __restrict__ w_hh,
                         char* __restrict__ wpre) {
  int bi = blockIdx.x;                 // (cg*4+q)*12+st, 3072 blocks
  int st = bi % 12, t2 = bi / 12, q = t2 & 3, cg = t2 >> 2;
  int t = threadIdx.x; if (t >= 192) return;
  int r = t >> 2, c = t & 3;
  int g = r >> 4, bn = r & 15;
  int k0 = q * 384 + st * 32 + c * 8;
  const float* src = (k0 < 512)
    ? (w_ih + (size_t)(g * 1024 + cg * 16 + bn) * EMBd + k0)
    : (w_hh + (size_t)(g * 1024 + cg * 16 + bn) * Hd + (k0 - 512));
  float4 v0 = *(const float4*)src, v1 = *(const float4*)(src + 4);
  half8 hh, ll; cvt8(v0, v1, hh, ll);
  char* d = wpre + (size_t)bi * 6144 + r * 128;
  *(half8*)(d + ((c       ^ (r & 7))) * 16) = hh;
  *(half8*)(d + (((c + 4) ^ (r & 7))) * 16) = ll;
}

// clspre: [ct 128][st 32][64 rows][128B], swizzled
__global__ void k_prep_cls(const float* __restrict__ cls_w, char* __restrict__ clsp) {
  int b = blockIdx.x;                  // ct*32+st, 4096 blocks
  int ct = b >> 5, st = b & 31;
  int t = threadIdx.x;
  int r = t >> 2, c = t & 3;
  const float* src = cls_w + (size_t)(ct * 64 + r) * Hd + st * 32 + c * 8;
  float4 v0 = *(const float4*)src, v1 = *(const float4*)(src + 4);
  half8 hh, ll; cvt8(v0, v1, hh, ll);
  char* d = clsp + (size_t)b * 8192 + r * 128;
  *(half8*)(d + ((c       ^ (r & 7))) * 16) = hh;
  *(half8*)(d + (((c + 4) ^ (r & 7))) * 16) = ll;
}

// ---------------------------------------------------------- grid barrier
// Two-level: 8 group counters (stride 64B) -> root. Agent-scope acq_rel.
__device__ __forceinline__ void gbar(uint32_t* __restrict__ bar, int wg, uint32_t gen) {
  __syncthreads();
  if (threadIdx.x == 0) {
    __threadfence();
    const int g = wg & 7;
    uint32_t old = __hip_atomic_fetch_add(&bar[g * 16], 1u, __ATOMIC_ACQ_REL,
                                          __HIP_MEMORY_SCOPE_AGENT);
    if (old + 1u == gen * 32u)
      __hip_atomic_fetch_add(&bar[128], 1u, __ATOMIC_ACQ_REL,
                             __HIP_MEMORY_SCOPE_AGENT);
    while (__hip_atomic_load(&bar[128], __ATOMIC_ACQUIRE,
                             __HIP_MEMORY_SCOPE_AGENT) < gen * 8u)
      __builtin_amdgcn_s_sleep(8);
  }
  __syncthreads();
}

// ----------------------------------------------- persistent full-loop kernel
__global__ __launch_bounds__(512) void k_loop(
    const char* __restrict__ embp, const char* __restrict__ wpre,
    const char* __restrict__ clsp,
    const float* __restrict__ b_ih, const float* __restrict__ b_hh,
    const float* __restrict__ cls_b,
    float* __restrict__ hbuf, char* __restrict__ hpre,
    float* __restrict__ part, int* __restrict__ ticket,
    ull* __restrict__ amax, float* __restrict__ out,
    uint32_t* __restrict__ bar)
{
  const int wg = blockIdx.x;
  const int tid = threadIdx.x, lane = tid & 63, w = tid >> 6;

  __shared__ __align__(16) char smem[98304];   // 96KB -> 1 WG/CU guaranteed
  __shared__ int swin;

  // ---- gates-role invariants (cg = wg&63, q = wg>>6)
  const int cg = wg & 63, gq = wg >> 6;
  const int C = cg * 16;
  const int rlo = lane >> 3, c1 = lane & 7;
  const int b0 = w * 16 + rlo;
  const int cswz = (c1 ^ rlo) * 16;
  const char* g_bsrc = wpre + (size_t)((cg * 4 + gq) * 12) * 6144 + w * 768 + lane * 16;
  const char* hsrcP[2] = { hpre + w * 2048 + lane * 16,
                           hpre + 32 * Bb * 128 + w * 2048 + lane * 16 };
  char* gA = smem;                 // 3 * 16384
  char* gB = smem + 49152;         // 3 * 6144

  // ---- cls-role invariants (ct = wg&127, rt0 = wg>>7)
  const int ct = wg & 127, rt0 = wg >> 7;
  const int r0c = rt0 * 64, c0c = ct * 64;
  const char* c_bsrc = clsp + (size_t)ct * 262144 + w * 1024 + lane * 16;
  const char* c_asrcP[2] = { hpre + rt0 * 8192 + w * 1024 + lane * 16,
                             hpre + 32 * Bb * 128 + rt0 * 8192 + w * 1024 + lane * 16 };
  char* cA = smem;                 // 3 * 8192
  char* cB = smem + 24576;         // 3 * 8192
  ull (*cand)[4] = (ull(*)[4])(smem + 49152);

  // fragment offsets
  const int l15 = lane & 15, qd = lane >> 4, r7 = l15 & 7;
  const int g_offAH = (w * 16 + l15) * 128 + ((qd)     ^ r7) * 16;
  const int g_offAL = (w * 16 + l15) * 128 + ((qd + 4) ^ r7) * 16;
  const int g_offBH = l15 * 128 + ((qd)     ^ r7) * 16;
  const int g_offBL = l15 * 128 + ((qd + 4) ^ r7) * 16;
  const int wr = w >> 2, wc = w & 3;
  const int c_offAH = (wr * 32 + l15) * 128 + ((qd)     ^ r7) * 16;
  const int c_offAL = (wr * 32 + l15) * 128 + ((qd + 4) ^ r7) * 16;
  const int c_offBH = (wc * 16 + l15) * 128 + ((qd)     ^ r7) * 16;
  const int c_offBL = (wc * 16 + l15) * 128 + ((qd + 4) ^ r7) * 16;
  const int vcol = c0c + wc * 16 + l15;
  const float bias = cls_b[vcol];

  uint32_t gen = 0;

  for (int s = 1; s < Td; ++s) {
    const int pPrev = (s - 1) & 1, pCur = s & 1;

    // ======================= gates GEMM + fused GRU =======================
    {
      const ull* amax_prev = amax + (size_t)(s - 1) * Bb;
      const uint32_t sid0 = (~(uint32_t)amax_prev[b0]) & 8191u;
      const uint32_t sid1 = (~(uint32_t)amax_prev[b0 + 8]) & 8191u;
      const char* esrc0 = embp + (size_t)sid0 * 2048 + cswz;
      const char* esrc1 = embp + (size_t)sid1 * 2048 + cswz;
      const char* hsrc = hsrcP[pPrev];
      asm volatile("" :: "v"(esrc0), "v"(esrc1));   // sidx consumed pre-DMA

      f32x4 accH[6], accL[6];
#pragma unroll
      for (int g = 0; g < 6; ++g) {
        accH[g] = (f32x4){0.f, 0.f, 0.f, 0.f};
        accL[g] = (f32x4){0.f, 0.f, 0.f, 0.f};
      }

      auto issue = [&](int st) {
        char* da = gA + (st % 3) * 16384 + w * 2048;
        const int k0 = gq * 384 + st * 32;
        if (k0 < 512) {
          const int o = (k0 >> 5) * 128;
          dma16(esrc0 + o, da);
          dma16(esrc1 + o, da + 1024);
        } else {
          const char* sp = hsrc + ((k0 - 512) >> 5) * 16384;
          dma16(sp, da);
          dma16(sp + 1024, da + 1024);
        }
        if (lane < 48) dma16(g_bsrc + st * 6144, gB + (st % 3) * 6144 + w * 768);
      };

      issue(0); issue(1);
      asm volatile("s_waitcnt vmcnt(3)" ::: "memory");
      __builtin_amdgcn_sched_barrier(0);
      __builtin_amdgcn_s_barrier();

#define GATE3(GB_)                                                             \
  _Pragma("unroll")                                                            \
  for (int g = 0; g < 3; ++g) {                                                \
    half8 bH = *(half8*)&gB[bf * 6144 + g * 2048 + g_offBH];                   \
    half8 bL = *(half8*)&gB[bf * 6144 + g * 2048 + g_offBL];                   \
    accH[GB_ + g] = __builtin_amdgcn_mfma_f32_16x16x32_f16(aH, bH, accH[GB_ + g], 0, 0, 0); \
    accL[GB_ + g] = __builtin_amdgcn_mfma_f32_16x16x32_f16(aH, bL, accL[GB_ + g], 0, 0, 0); \
    accL[GB_ + g] = __builtin_amdgcn_mfma_f32_16x16x32_f16(aL, bH, accL[GB_ + g], 0, 0, 0); \
  }

      for (int st = 0; st < 12; ++st) {
        const int bf = st % 3;
        const bool eph = (gq * 384 + st * 32) < 512;
        half8 aH = *(half8*)&gA[bf * 16384 + g_offAH];
        half8 aL = *(half8*)&gA[bf * 16384 + g_offAL];
        if (st + 2 < 12) issue(st + 2);
        if (eph) { GATE3(0) } else { GATE3(3) }
        if (st < 11) {
          if (st < 10) asm volatile("s_waitcnt vmcnt(3)" ::: "memory");
          else         asm volatile("s_waitcnt vmcnt(0)" ::: "memory");
          __builtin_amdgcn_sched_barrier(0);
          asm volatile("s_waitcnt lgkmcnt(0)" ::: "memory");
          __builtin_amdgcn_sched_barrier(0);
          __builtin_amdgcn_s_barrier();
        }
      }
#undef GATE3

      {  // store partials: D layout col=lane&15, row=(lane>>4)*4+i [m89]
        float* base = part + (size_t)(gq * 64 + cg) * 6 * 2048;
        const int q4 = qd * 4;
        const int row = w * 16 + q4;
#pragma unroll
        for (int gs = 0; gs < 6; ++gs)
#pragma unroll
          for (int i = 0; i < 4; ++i)
            base[gs * 2048 + (row + i) * 16 + l15] = accH[gs][i] + accL[gs][i] * LOINV;
      }

      __syncthreads();
      if (tid == 0) {
        __threadfence();
        int old = __hip_atomic_fetch_add(&ticket[cg], 1, __ATOMIC_ACQ_REL,
                                         __HIP_MEMORY_SCOPE_AGENT);
        swin = (old == 3);
      }
      __syncthreads();

      if (swin) {
        const float* hprev_f = hbuf + (size_t)pPrev * Bb * Hd;
        float* hnew_f = hbuf + (size_t)pCur * Bb * Hd;
        char* hpre_new = hpre + (size_t)pCur * 32 * Bb * 128;
        if (tid < 256) {
          const int b = tid >> 1, hf = tid & 1;
          const int j0 = C + hf * 8;
          float gv[6][8];
#pragma unroll
          for (int gs = 0; gs < 6; ++gs)
#pragma unroll
            for (int i = 0; i < 8; ++i) gv[gs][i] = 0.f;
          for (int q2 = 0; q2 < 4; ++q2) {
            const float* p = part + (size_t)(q2 * 64 + cg) * 6 * 2048 + b * 16 + hf * 8;
#pragma unroll
            for (int gs = 0; gs < 6; ++gs)
#pragma unroll
              for (int i = 0; i < 8; ++i) gv[gs][i] += p[gs * 2048 + i];
          }
          float outs[8];
#pragma unroll
          for (int i = 0; i < 8; ++i) {
            const int j = j0 + i;
            float ir = gv[0][i] + b_ih[j], iz = gv[1][i] + b_ih[1024 + j], in_ = gv[2][i] + b_ih[2048 + j];
            float hr = gv[3][i] + b_hh[j], hz = gv[4][i] + b_hh[1024 + j], hn = gv[5][i] + b_hh[2048 + j];
            float rr = 1.f / (1.f + expf(-(ir + hr)));
            float zz = 1.f / (1.f + expf(-(iz + hz)));
            float nn = tanhf(in_ + rr * hn);
            outs[i] = (1.f - zz) * nn + zz * hprev_f[b * Hd + j];
          }
          *(float4*)(hnew_f + b * Hd + j0)     = (float4){outs[0], outs[1], outs[2], outs[3]};
          *(float4*)(hnew_f + b * Hd + j0 + 4) = (float4){outs[4], outs[5], outs[6], outs[7]};
          half8 hh, ll;
#pragma unroll
          for (int i = 0; i < 8; ++i) {
            _Float16 h = (_Float16)outs[i];
            hh[i] = h; ll[i] = (_Float16)((outs[i] - (float)h) * LOSCALE);
          }
          const int stp = j0 >> 5;
          const int chi = (j0 & 31) >> 3;
          char* hp = hpre_new + stp * 16384 + b * 128;
          *(half8*)(hp + ((chi       ^ (b & 7))) * 16) = hh;
          *(half8*)(hp + (((chi + 4) ^ (b & 7))) * 16) = ll;
        }
        if (tid == 0)
          __hip_atomic_store(&ticket[cg], 0, __ATOMIC_RELAXED, __HIP_MEMORY_SCOPE_AGENT);
      }
    }

    ++gen; gbar(bar, wg, gen);   // h tiles visible to all

    // ======================= cls GEMM + argmax =======================
    {
      const char* asrc = c_asrcP[pCur];
      f32x4 accH[2], accL[2];
#pragma unroll
      for (int i = 0; i < 2; ++i) {
        accH[i] = (f32x4){0.f, 0.f, 0.f, 0.f};
        accL[i] = (f32x4){0.f, 0.f, 0.f, 0.f};
      }

      auto issue = [&](int st) {
        dma16(asrc + st * 16384, cA + (st % 3) * 8192 + w * 1024);
        dma16(c_bsrc + st * 8192, cB + (st % 3) * 8192 + w * 1024);
      };

      issue(0); issue(1);
      asm volatile("s_waitcnt vmcnt(2)" ::: "memory");
      __builtin_amdgcn_sched_barrier(0);
      __builtin_amdgcn_s_barrier();

      for (int st = 0; st < 32; ++st) {
        const int bf = st % 3;
        half8 aH0 = *(half8*)&cA[bf * 8192 + c_offAH];
        half8 aL0 = *(half8*)&cA[bf * 8192 + c_offAL];
        half8 aH1 = *(half8*)&cA[bf * 8192 + c_offAH + 2048];
        half8 aL1 = *(half8*)&cA[bf * 8192 + c_offAL + 2048];
        half8 bH  = *(half8*)&cB[bf * 8192 + c_offBH];
        half8 bL  = *(half8*)&cB[bf * 8192 + c_offBL];
        if (st + 2 < 32) issue(st + 2);
        accH[0] = __builtin_amdgcn_mfma_f32_16x16x32_f16(aH0, bH, accH[0], 0, 0, 0);
        accL[0] = __builtin_amdgcn_mfma_f32_16x16x32_f16(aH0, bL, accL[0], 0, 0, 0);
        accL[0] = __builtin_amdgcn_mfma_f32_16x16x32_f16(aL0, bH, accL[0], 0, 0, 0);
        accH[1] = __builtin_amdgcn_mfma_f32_16x16x32_f16(aH1, bH, accH[1], 0, 0, 0);
        accL[1] = __builtin_amdgcn_mfma_f32_16x16x32_f16(aH1, bL, accL[1], 0, 0, 0);
        accL[1] = __builtin_amdgcn_mfma_f32_16x16x32_f16(aL1, bH, accL[1], 0, 0, 0);
        if (st < 31) {
          if (st < 30) asm volatile("s_waitcnt vmcnt(2)" ::: "memory");
          else         asm volatile("s_waitcnt vmcnt(0)" ::: "memory");
          __builtin_amdgcn_sched_barrier(0);
          asm volatile("s_waitcnt lgkmcnt(0)" ::: "memory");
          __builtin_amdgcn_sched_barrier(0);
          __builtin_amdgcn_s_barrier();
        }
      }

      // epilogue: +bias, store raw logits, packed (max,argmax) -> atomicMax
#pragma unroll
      for (int rt = 0; rt < 2; ++rt) {
        ull best[4];
#pragma unroll
        for (int i = 0; i < 4; ++i) {
          float val = accH[rt][i] + accL[rt][i] * LOINV + bias;
          const int brow = r0c + wr * 32 + rt * 16 + qd * 4 + i;
          out[((size_t)brow * Td + s) * Vd + vcol] = val;
          best[i] = ((ull)fkey(val) << 32) | (uint32_t)(~(uint32_t)vcol);
        }
#pragma unroll
        for (int i = 0; i < 4; ++i) {
          ull bb = best[i];
          bb = umax64(bb, __shfl_xor(bb, 1));
          bb = umax64(bb, __shfl_xor(bb, 2));
          bb = umax64(bb, __shfl_xor(bb, 4));
          bb = umax64(bb, __shfl_xor(bb, 8));
          if (l15 == 0) cand[wr * 32 + rt * 16 + qd * 4 + i][wc] = bb;
        }
      }
      __syncthreads();
      if (tid < 64) {
        ull m_ = umax64(umax64(cand[tid][0], cand[tid][1]),
                        umax64(cand[tid][2], cand[tid][3]));
        atomicMax(&amax[(size_t)s * Bb + r0c + tid], m_);
      }
    }

    ++gen; gbar(bar, wg, gen);   // amax visible for next step's gather
  }
}

// -------------------------------------------------- final log_softmax pass
__global__ void k_softmax(float* __restrict__ out,
                          const ull* __restrict__ amax) {
  int blk = blockIdx.x;           // 12800 = 128*100
  int t = blk % Td, b = blk / Td;
  int tid = threadIdx.x;
  float* row = out + ((size_t)b * Td + t) * Vd;
  if (t == 0) {
    float lse0 = logf(expf(1.0f) + (float)(Vd - 1));
    for (int i = tid; i < Vd; i += 256) row[i] = ((i == 0) ? 1.0f : 0.0f) - lse0;
    return;
  }
  ull key = amax[t * Bb + b];
  uint32_t ku = (uint32_t)(key >> 32);
  uint32_t u = (ku & 0x80000000u) ? (ku & 0x7fffffffu) : ~ku;
  float m = __uint_as_float(u);
  float x[32];
  float ssum = 0.f;
#pragma unroll
  for (int i = 0; i < 32; ++i) {
    x[i] = row[tid + i * 256];
    ssum += expf(x[i] - m);
  }
  ssum += __shfl_xor(ssum, 1);
  ssum += __shfl_xor(ssum, 2);
  ssum += __shfl_xor(ssum, 4);
  ssum += __shfl_xor(ssum, 8);
  ssum += __shfl_xor(ssum, 16);
  ssum += __shfl_xor(ssum, 32);
  __shared__ float wsum[4];
  if ((tid & 63) == 0) wsum[tid >> 6] = ssum;
  __syncthreads();
  float lse = m + logf(wsum[0] + wsum[1] + wsum[2] + wsum[3]);
#pragma unroll
  for (int i = 0; i < 32; ++i) row[tid + i * 256] = x[i] - lse;
}

// ----------------------------------------------------------------- launch
extern "C" void kernel_launch(void* const* d_in, const int* in_sizes, int n_in,
                              void* d_out, int out_size, void* d_ws, size_t ws_size,
                              hipStream_t stream) {
  const float* x     = (const float*)d_in[0];
  const float* emb   = (const float*)d_in[1];
  const float* w_ih  = (const float*)d_in[2];
  const float* w_hh  = (const float*)d_in[3];
  const float* b_ih  = (const float*)d_in[4];
  const float* b_hh  = (const float*)d_in[5];
  const float* cls_w = (const float*)d_in[6];
  const float* cls_b = (const float*)d_in[7];
  float* out = (float*)d_out;

  char* ws = (char*)d_ws;
  size_t o = 0;
  ull*      amax   = (ull*)(ws + o);      o += (size_t)Td * Bb * 8;        // 100 KB
  int*      ticket = (int*)(ws + o);      o += 1024;
  uint32_t* bar    = (uint32_t*)(ws + o); o += 1024;
  float*    hbuf   = (float*)(ws + o);    o += (size_t)2 * Bb * Hd * 4;    // 1 MB
  float*    part   = (float*)(ws + o);    o += (size_t)4 * 64 * 6 * 2048 * 4; // 12.6 MB
  char*     hpre   = ws + o;              o += (size_t)2 * 32 * Bb * 128;  // 1 MB
  char*     embp   = ws + o;              o += (size_t)Vd * 2048;          // 16.8 MB
  char*     wpre   = ws + o;              o += (size_t)3072 * 6144;        // 18.9 MB
  char*     clsp   = ws + o;              o += (size_t)128 * 32 * 8192;    // 33.6 MB

  k_init<<<512, 256, 0, stream>>>(x, hbuf, amax, ticket, hpre, bar);
  k_prep_emb<<<2048, 256, 0, stream>>>(emb, embp);
  k_prep_w<<<3072, 256, 0, stream>>>(w_ih, w_hh, wpre);
  k_prep_cls<<<4096, 256, 0, stream>>>(cls_w, clsp);

  k_loop<<<NWG, 512, 0, stream>>>(embp, wpre, clsp, b_ih, b_hh, cls_b,
                                  hbuf, hpre, part, ticket, amax, out, bar);

  k_softmax<<<12800, 256, 0, stream>>>(out, amax);
}

// Round 4
// 6692.324 us; speedup vs baseline: 2.6723x; 2.6723x over previous
//
#include <hip/hip_runtime.h>
#include <stdint.h>

// SequenceDecoder: B=128, EMB=512, H=1024, V=8192, T=100 (99 sequential steps).
//  - argmax(log_softmax) == argmax(raw): recurrence needs only raw-logit argmax.
//  - fp16 hi/lo split GEMMs (3 MFMA passes, lo x2048) ~22 mantissa bits.
//  - Weights pre-converted ONCE to fp16 hi|lo tile images with the LDS
//    XOR-swizzle (chunk ^= row&7) baked in. All K-loop staging is
//    global_load_lds width-16 DMA. Quad-buffered LDS, counted vmcnt (never 0
//    mid-loop), raw s_barrier.
//  - NEW (r4): gi-table precompute: gi = emb @ w_ih.T + b_ih for ALL 8192
//    vocab rows, once (~40us). Gates GEMM is then h-part only (K=1024), with
//    NO part buffer / NO ticket / NO gather on the DMA path; GRU fused in the
//    epilogue (i-gates gathered from gi by argmax). cls widened to 512 WGs x
//    256 thr (48KB LDS -> 2 WGs/CU) for TLP latency hiding.
//  - r3 persistent-kernel experiment REVERTED: grid-barrier acquires
//    invalidated per-XCD L2 every step (FETCH showed full 52.5MB/step weight
//    refetch) -> 3.4x regression.

#define Bb   128
#define EMBd 512
#define Hd   1024
#define Vd   8192
#define Td   100

typedef __attribute__((ext_vector_type(8))) _Float16 half8;
typedef __attribute__((ext_vector_type(4))) float f32x4;
typedef unsigned long long ull;

#define LOSCALE 2048.0f
#define LOINV   (1.0f/2048.0f)

#define WAITV(N) do { asm volatile("s_waitcnt vmcnt(" #N ")" ::: "memory"); \
                      __builtin_amdgcn_sched_barrier(0); } while (0)
#define WAITL    do { asm volatile("s_waitcnt lgkmcnt(0)" ::: "memory");    \
                      __builtin_amdgcn_sched_barrier(0); } while (0)

__device__ __forceinline__ uint32_t fkey(float f) {
  uint32_t u = __float_as_uint(f);
  return (u & 0x80000000u) ? ~u : (u | 0x80000000u);
}
__device__ __forceinline__ ull umax64(ull a, ull b) { return a > b ? a : b; }

__device__ __forceinline__ void dma16(const void* g, void* l) {
  __builtin_amdgcn_global_load_lds((const uint32_t*)g, (uint32_t*)l, 16, 0, 0);
}

// split 8 fp32 into fp16 hi + (lo*2048)
__device__ __forceinline__ void cvt8(const float4 v0, const float4 v1,
                                     half8& hh, half8& ll) {
  float vv[8] = {v0.x, v0.y, v0.z, v0.w, v1.x, v1.y, v1.z, v1.w};
#pragma unroll
  for (int i = 0; i < 8; ++i) {
    _Float16 h = (_Float16)vv[i];
    hh[i] = h;
    ll[i] = (_Float16)((vv[i] - (float)h) * LOSCALE);
  }
}

// ---------------------------------------------------------------- init
// also converts x -> hpre0 swizzled fp16 tile [st32][b128][8 chunks of 16B]
__global__ void k_init(const float* __restrict__ x, float* __restrict__ hbuf0,
                       ull* __restrict__ amax, char* __restrict__ hpre0) {
  int tid = blockIdx.x * 256 + threadIdx.x;
  if (tid < Bb * Hd) hbuf0[tid] = x[tid];
  if (tid < Td * Bb) amax[tid] = (tid < Bb) ? 0xFFFFFFFFull : 0ull;  // t=0: idx=0
  if (tid < 16384) {
    int b = tid & 127, sc = tid >> 7;
    int st = sc >> 2, c = sc & 3;
    const float* src = x + b * Hd + st * 32 + c * 8;
    float4 v0 = *(const float4*)src, v1 = *(const float4*)(src + 4);
    half8 hh, ll; cvt8(v0, v1, hh, ll);
    char* hp = hpre0 + st * 16384 + b * 128;
    *(half8*)(hp + ((c       ^ (b & 7))) * 16) = hh;
    *(half8*)(hp + (((c + 4) ^ (b & 7))) * 16) = ll;
  }
}

// ------------------------------------------------------------- prep kernels
// emb_pre: [row 8192][st_e 16][chunk 8][16B], UNSWIZZLED (per-lane swizzled
// source addresses applied at DMA time in k_prep_gi)
__global__ void k_prep_emb(const float* __restrict__ emb, char* __restrict__ embp) {
  int t = blockIdx.x * 256 + threadIdx.x;          // 524288 total
  int row = t >> 6, rem = t & 63, st = rem >> 2, c = rem & 3;
  const float* src = emb + (size_t)row * EMBd + st * 32 + c * 8;
  float4 v0 = *(const float4*)src, v1 = *(const float4*)(src + 4);
  half8 hh, ll; cvt8(v0, v1, hh, ll);
  char* d = embp + (size_t)row * 2048 + st * 128;
  *(half8*)(d + c * 16) = hh;
  *(half8*)(d + (c + 4) * 16) = ll;
}

// wpre: per (cg,q,st) tile: [48 rows][128B], swizzled (chunk ^= r&7)
// combined K: [0,512)=w_ih (e-part), [512,1536)=w_hh (h-part)
__global__ void k_prep_w(const float* __restrict__ w_ih, const float* __restrict__ w_hh,
                         char* __restrict__ wpre) {
  int bi = blockIdx.x;                 // (cg*4+q)*12+st, 3072 blocks
  int st = bi % 12, t2 = bi / 12, q = t2 & 3, cg = t2 >> 2;
  int t = threadIdx.x; if (t >= 192) return;
  int r = t >> 2, c = t & 3;
  int g = r >> 4, bn = r & 15;
  int k0 = q * 384 + st * 32 + c * 8;
  const float* src = (k0 < 512)
    ? (w_ih + (size_t)(g * 1024 + cg * 16 + bn) * EMBd + k0)
    : (w_hh + (size_t)(g * 1024 + cg * 16 + bn) * Hd + (k0 - 512));
  float4 v0 = *(const float4*)src, v1 = *(const float4*)(src + 4);
  half8 hh, ll; cvt8(v0, v1, hh, ll);
  char* d = wpre + (size_t)bi * 6144 + r * 128;
  *(half8*)(d + ((c       ^ (r & 7))) * 16) = hh;
  *(half8*)(d + (((c + 4) ^ (r & 7))) * 16) = ll;
}

// clspre: [ct 128][st 32][64 rows][128B], swizzled
__global__ void k_prep_cls(const float* __restrict__ cls_w, char* __restrict__ clsp) {
  int b = blockIdx.x;                  // ct*32+st, 4096 blocks
  int ct = b >> 5, st = b & 31;
  int t = threadIdx.x;
  int r = t >> 2, c = t & 3;
  const float* src = cls_w + (size_t)(ct * 64 + r) * Hd + st * 32 + c * 8;
  float4 v0 = *(const float4*)src, v1 = *(const float4*)(src + 4);
  half8 hh, ll; cvt8(v0, v1, hh, ll);
  char* d = clsp + (size_t)b * 8192 + r * 128;
  *(half8*)(d + ((c       ^ (r & 7))) * 16) = hh;
  *(half8*)(d + (((c + 4) ^ (r & 7))) * 16) = ll;
}

// ------------------------------------------- gi table: emb @ w_ih.T + b_ih
// gi[v][gate3][j 1024] fp32. grid (64 cg, 128 vh) x 256 thr; K=512 = 16 st.
__global__ __launch_bounds__(256, 2) void k_prep_gi(
    const char* __restrict__ embp, const char* __restrict__ wpre,
    const float* __restrict__ b_ih, float* __restrict__ gi)
{
  const int cg = blockIdx.x, vh = blockIdx.y;
  const int tid = threadIdx.x, lane = tid & 63, w = tid >> 6;
  const int C = cg * 16;
  __shared__ __align__(16) char pA[4 * 8192];
  __shared__ __align__(16) char pB[4 * 6144];

  f32x4 accH[3], accL[3];
#pragma unroll
  for (int g = 0; g < 3; ++g) {
    accH[g] = (f32x4){0.f, 0.f, 0.f, 0.f};
    accL[g] = (f32x4){0.f, 0.f, 0.f, 0.f};
  }

  const int rr = lane >> 3, cc = lane & 7;
  const char* abase = embp + (size_t)(vh * 64 + w * 16 + rr) * 2048 + ((cc ^ rr) * 16);

  auto issue = [&](int st) {
    char* da = pA + (st & 3) * 8192 + w * 2048;
    const char* s0 = abase + st * 128;
    dma16(s0, da);
    dma16(s0 + 8 * 2048, da + 1024);
    const int wq = st / 12, wst = st - wq * 12;
    const char* sb = wpre + (size_t)((cg * 4 + wq) * 12 + wst) * 6144 + w * 1536 + lane * 16;
    char* db = pB + (st & 3) * 6144 + w * 1536;
    dma16(sb, db);
    if (lane < 32) dma16(sb + 1024, db + 1024);
  };

  const int l15 = lane & 15, qd = lane >> 4, r7 = l15 & 7;
  const int offAH = (w * 16 + l15) * 128 + ((qd)     ^ r7) * 16;
  const int offAL = (w * 16 + l15) * 128 + ((qd + 4) ^ r7) * 16;

  issue(0); issue(1); issue(2);
  WAITV(8);
  __builtin_amdgcn_s_barrier();

  for (int st = 0; st < 16; ++st) {
    const int bf = st & 3;
    half8 aH = *(half8*)&pA[bf * 8192 + offAH];
    half8 aL = *(half8*)&pA[bf * 8192 + offAL];
    if (st + 3 < 16) issue(st + 3);
#pragma unroll
    for (int g = 0; g < 3; ++g) {
      half8 bH = *(half8*)&pB[bf * 6144 + g * 2048 + (g * 0) + ((g * 16 + l15) * 128 - g * 2048) + ((qd) ^ r7) * 16];
      half8 bL = *(half8*)&pB[bf * 6144 + (g * 16 + l15) * 128 + ((qd + 4) ^ r7) * 16];
      accH[g] = __builtin_amdgcn_mfma_f32_16x16x32_f16(aH, bH, accH[g], 0, 0, 0);
      accL[g] = __builtin_amdgcn_mfma_f32_16x16x32_f16(aH, bL, accL[g], 0, 0, 0);
      accL[g] = __builtin_amdgcn_mfma_f32_16x16x32_f16(aL, bH, accL[g], 0, 0, 0);
    }
    if (st < 15) {
      if (st <= 12)      { WAITV(8); }
      else if (st == 13) { WAITV(4); }
      else               { WAITV(0); }
      WAITL;
      __builtin_amdgcn_s_barrier();
    }
  }

  const int v0 = vh * 64 + w * 16 + qd * 4;
#pragma unroll
  for (int g = 0; g < 3; ++g) {
    float bi = b_ih[g * 1024 + C + l15];
#pragma unroll
    for (int i = 0; i < 4; ++i) {
      float val = accH[g][i] + accL[g][i] * LOINV + bi;
      gi[(size_t)(v0 + i) * 3072 + g * 1024 + C + l15] = val;
    }
  }
}

// --------------------------- gates GEMM (h-part only, K=1024) + fused GRU
// grid (64 cg, 2 rh) x 256 thr. 4 waves x 16 rows; 16 j-cols; 3 h-gates.
// DMA 4 ops/wave/iter (A 2 + B 2), quad-buffer, depth-3 counted vmcnt.
// Epilogue: gather i-gates from gi[argmax_prev], GRU, write hnew fp32 +
// swizzled fp16 hi/lo h-tile for the next GEMMs.
__global__ __launch_bounds__(256) void k_gates2(
    const char* __restrict__ wpre, const float* __restrict__ gi,
    const char* __restrict__ hpre_prev, const ull* __restrict__ amax_prev,
    const float* __restrict__ b_hh, const float* __restrict__ hprev_f,
    float* __restrict__ hnew_f, char* __restrict__ hpre_new)
{
  const int cg = blockIdx.x, rh = blockIdx.y;
  const int tid = threadIdx.x, lane = tid & 63, w = tid >> 6;
  const int C = cg * 16;
  __shared__ __align__(16) char gAs[4 * 8192];
  __shared__ __align__(16) char gBs[4 * 6144];

  f32x4 accH[3], accL[3];
#pragma unroll
  for (int g = 0; g < 3; ++g) {
    accH[g] = (f32x4){0.f, 0.f, 0.f, 0.f};
    accL[g] = (f32x4){0.f, 0.f, 0.f, 0.f};
  }

  const char* abase = hpre_prev + rh * 8192 + w * 2048 + lane * 16;   // +st*16384

  auto issue = [&](int st) {
    char* da = gAs + (st & 3) * 8192 + w * 2048;
    const char* sa = abase + st * 16384;
    dma16(sa, da);
    dma16(sa + 1024, da + 1024);
    const int k0 = 512 + st * 32;
    const int wq = (k0 >= 1152) ? 3 : (k0 >= 768 ? 2 : 1);
    const int wst = (k0 - wq * 384) >> 5;
    const char* sb = wpre + (size_t)((cg * 4 + wq) * 12 + wst) * 6144 + w * 1536 + lane * 16;
    char* db = gBs + (st & 3) * 6144 + w * 1536;
    dma16(sb, db);
    if (lane < 32) dma16(sb + 1024, db + 1024);
  };

  const int l15 = lane & 15, qd = lane >> 4, r7 = l15 & 7;
  const int offAH = (w * 16 + l15) * 128 + ((qd)     ^ r7) * 16;
  const int offAL = (w * 16 + l15) * 128 + ((qd + 4) ^ r7) * 16;

  issue(0); issue(1); issue(2);
  WAITV(8);
  __builtin_amdgcn_s_barrier();

  for (int st = 0; st < 32; ++st) {
    const int bf = st & 3;
    half8 aH = *(half8*)&gAs[bf * 8192 + offAH];
    half8 aL = *(half8*)&gAs[bf * 8192 + offAL];
    if (st + 3 < 32) issue(st + 3);
#pragma unroll
    for (int g = 0; g < 3; ++g) {
      half8 bH = *(half8*)&gBs[bf * 6144 + (g * 16 + l15) * 128 + ((qd)     ^ r7) * 16];
      half8 bL = *(half8*)&gBs[bf * 6144 + (g * 16 + l15) * 128 + ((qd + 4) ^ r7) * 16];
      accH[g] = __builtin_amdgcn_mfma_f32_16x16x32_f16(aH, bH, accH[g], 0, 0, 0);
      accL[g] = __builtin_amdgcn_mfma_f32_16x16x32_f16(aH, bL, accL[g], 0, 0, 0);
      accL[g] = __builtin_amdgcn_mfma_f32_16x16x32_f16(aL, bH, accL[g], 0, 0, 0);
    }
    if (st < 31) {
      if (st <= 28)      { WAITV(8); }
      else if (st == 29) { WAITV(4); }
      else               { WAITV(0); }
      WAITL;
      __builtin_amdgcn_s_barrier();
    }
  }

  // epilogue: GRU per lane: 4 rows (qd*4+i) x 1 col (j = C+l15)
  const int j = C + l15;
  const float bh0 = b_hh[j], bh1 = b_hh[1024 + j], bh2 = b_hh[2048 + j];
  const int stp = j >> 5, ch = (j & 31) >> 3, e2 = (j & 7) * 2;
#pragma unroll
  for (int i = 0; i < 4; ++i) {
    const int ri = rh * 64 + w * 16 + qd * 4 + i;
    const uint32_t idx = (~(uint32_t)amax_prev[ri]) & 8191u;
    const float* gp = gi + (size_t)idx * 3072 + j;
    float i_r = gp[0], i_z = gp[1024], i_n = gp[2048];
    float h_r = accH[0][i] + accL[0][i] * LOINV + bh0;
    float h_z = accH[1][i] + accL[1][i] * LOINV + bh1;
    float h_n = accH[2][i] + accL[2][i] * LOINV + bh2;
    float rr2 = 1.f / (1.f + expf(-(i_r + h_r)));
    float zz = 1.f / (1.f + expf(-(i_z + h_z)));
    float nn = tanhf(i_n + rr2 * h_n);
    float o = (1.f - zz) * nn + zz * hprev_f[ri * Hd + j];
    hnew_f[ri * Hd + j] = o;
    _Float16 oh = (_Float16)o;
    _Float16 ol = (_Float16)((o - (float)oh) * LOSCALE);
    char* hp8 = hpre_new + stp * 16384 + ri * 128;
    *(_Float16*)(hp8 + ((ch     ^ (ri & 7)) * 16 + e2)) = oh;
    *(_Float16*)(hp8 + (((ch + 4) ^ (ri & 7)) * 16 + e2)) = ol;
  }
}

// ----------------------------------------------- cls GEMM + argmax atomics
// grid (256 ctn, 2 rt0) x 256 thr: 64-row x 32-col tiles, 4 waves x 16 rows
// x 2 col-frags. 48KB LDS -> 2 WGs/CU (TLP). DMA 3 ops/wave/iter, depth-3.
__global__ __launch_bounds__(256, 2) void k_cls2(
    const char* __restrict__ hpre_c, const char* __restrict__ clsp,
    const float* __restrict__ cls_b, float* __restrict__ out,
    ull* __restrict__ amax_s, int s)
{
  const int ctn = blockIdx.x, rt0 = blockIdx.y;
  const int tid = threadIdx.x, lane = tid & 63, w = tid >> 6;
  const int c0 = ctn * 32, r0 = rt0 * 64;
  __shared__ __align__(16) char cAs[4 * 8192];
  __shared__ __align__(16) char cBs[4 * 4096];

  f32x4 accH[2], accL[2];
#pragma unroll
  for (int i = 0; i < 2; ++i) {
    accH[i] = (f32x4){0.f, 0.f, 0.f, 0.f};
    accL[i] = (f32x4){0.f, 0.f, 0.f, 0.f};
  }

  const char* abase = hpre_c + rt0 * 8192 + w * 2048 + lane * 16;   // +st*16384
  const char* bbase = clsp + (size_t)(ctn >> 1) * 262144 + (ctn & 1) * 4096
                      + w * 1024 + lane * 16;                        // +st*8192

  auto issue = [&](int st) {
    char* da = cAs + (st & 3) * 8192 + w * 2048;
    const char* sa = abase + st * 16384;
    dma16(sa, da);
    dma16(sa + 1024, da + 1024);
    dma16(bbase + st * 8192, cBs + (st & 3) * 4096 + w * 1024);
  };

  const int l15 = lane & 15, qd = lane >> 4, r7 = l15 & 7;
  const int offAH = (w * 16 + l15) * 128 + ((qd)     ^ r7) * 16;
  const int offAL = (w * 16 + l15) * 128 + ((qd + 4) ^ r7) * 16;

  issue(0); issue(1); issue(2);
  WAITV(6);
  __builtin_amdgcn_s_barrier();

  for (int st = 0; st < 32; ++st) {
    const int bf = st & 3;
    half8 aH = *(half8*)&cAs[bf * 8192 + offAH];
    half8 aL = *(half8*)&cAs[bf * 8192 + offAL];
    if (st + 3 < 32) issue(st + 3);
#pragma unroll
    for (int cf = 0; cf < 2; ++cf) {
      half8 bH = *(half8*)&cBs[bf * 4096 + (cf * 16 + l15) * 128 + ((qd)     ^ r7) * 16];
      half8 bL = *(half8*)&cBs[bf * 4096 + (cf * 16 + l15) * 128 + ((qd + 4) ^ r7) * 16];
      accH[cf] = __builtin_amdgcn_mfma_f32_16x16x32_f16(aH, bH, accH[cf], 0, 0, 0);
      accL[cf] = __builtin_amdgcn_mfma_f32_16x16x32_f16(aH, bL, accL[cf], 0, 0, 0);
      accL[cf] = __builtin_amdgcn_mfma_f32_16x16x32_f16(aL, bH, accL[cf], 0, 0, 0);
    }
    if (st < 31) {
      if (st <= 28)      { WAITV(6); }
      else if (st == 29) { WAITV(3); }
      else               { WAITV(0); }
      WAITL;
      __builtin_amdgcn_s_barrier();
    }
  }

  // epilogue: +bias, store raw logits, per-row packed (max,argmax) atomicMax
  const int vc0 = c0 + l15;
  const float b0v = cls_b[vc0], b1v = cls_b[vc0 + 16];
#pragma unroll
  for (int i = 0; i < 4; ++i) {
    float v0 = accH[0][i] + accL[0][i] * LOINV + b0v;
    float v1 = accH[1][i] + accL[1][i] * LOINV + b1v;
    const int brow = r0 + w * 16 + qd * 4 + i;
    float* orow = out + ((size_t)brow * Td + s) * Vd;
    orow[vc0] = v0;
    orow[vc0 + 16] = v1;
    ull k0 = ((ull)fkey(v0) << 32) | (uint32_t)(~(uint32_t)vc0);
    ull k1 = ((ull)fkey(v1) << 32) | (uint32_t)(~(uint32_t)(vc0 + 16));
    ull bb = umax64(k0, k1);
    bb = umax64(bb, __shfl_xor(bb, 1));
    bb = umax64(bb, __shfl_xor(bb, 2));
    bb = umax64(bb, __shfl_xor(bb, 4));
    bb = umax64(bb, __shfl_xor(bb, 8));
    if (l15 == 0) atomicMax(&amax_s[brow], bb);
  }
}

// -------------------------------------------------- final log_softmax pass
__global__ void k_softmax(float* __restrict__ out,
                          const ull* __restrict__ amax) {
  int blk = blockIdx.x;           // 12800 = 128*100
  int t = blk % Td, b = blk / Td;
  int tid = threadIdx.x;
  float* row = out + ((size_t)b * Td + t) * Vd;
  if (t == 0) {
    float lse0 = logf(expf(1.0f) + (float)(Vd - 1));
    for (int i = tid; i < Vd; i += 256) row[i] = ((i == 0) ? 1.0f : 0.0f) - lse0;
    return;
  }
  ull key = amax[t * Bb + b];
  uint32_t ku = (uint32_t)(key >> 32);
  uint32_t u = (ku & 0x80000000u) ? (ku & 0x7fffffffu) : ~ku;
  float m = __uint_as_float(u);
  float x[32];
  float ssum = 0.f;
#pragma unroll
  for (int i = 0; i < 32; ++i) {
    x[i] = row[tid + i * 256];
    ssum += expf(x[i] - m);
  }
  ssum += __shfl_xor(ssum, 1);
  ssum += __shfl_xor(ssum, 2);
  ssum += __shfl_xor(ssum, 4);
  ssum += __shfl_xor(ssum, 8);
  ssum += __shfl_xor(ssum, 16);
  ssum += __shfl_xor(ssum, 32);
  __shared__ float wsum[4];
  if ((tid & 63) == 0) wsum[tid >> 6] = ssum;
  __syncthreads();
  float lse = m + logf(wsum[0] + wsum[1] + wsum[2] + wsum[3]);
#pragma unroll
  for (int i = 0; i < 32; ++i) row[tid + i * 256] = x[i] - lse;
}

// ----------------------------------------------------------------- launch
extern "C" void kernel_launch(void* const* d_in, const int* in_sizes, int n_in,
                              void* d_out, int out_size, void* d_ws, size_t ws_size,
                              hipStream_t stream) {
  const float* x     = (const float*)d_in[0];
  const float* emb   = (const float*)d_in[1];
  const float* w_ih  = (const float*)d_in[2];
  const float* w_hh  = (const float*)d_in[3];
  const float* b_ih  = (const float*)d_in[4];
  const float* b_hh  = (const float*)d_in[5];
  const float* cls_w = (const float*)d_in[6];
  const float* cls_b = (const float*)d_in[7];
  float* out = (float*)d_out;

  char* ws = (char*)d_ws;
  size_t o = 0;
  ull*   amax = (ull*)(ws + o);    o += (size_t)Td * Bb * 8;          // 100 KB
  float* hbuf = (float*)(ws + o);  o += (size_t)2 * Bb * Hd * 4;      // 1 MB
  char*  hpre = ws + o;            o += (size_t)2 * 32 * Bb * 128;    // 1 MB
  char*  embp = ws + o;            o += (size_t)Vd * 2048;            // 16.8 MB
  char*  wpre = ws + o;            o += (size_t)3072 * 6144;          // 18.9 MB
  char*  clsp = ws + o;            o += (size_t)128 * 32 * 8192;      // 33.6 MB
  float* gi   = (float*)(ws + o);  o += (size_t)Vd * 3072 * 4;        // 100.7 MB

  k_init<<<512, 256, 0, stream>>>(x, hbuf, amax, hpre);
  k_prep_emb<<<2048, 256, 0, stream>>>(emb, embp);
  k_prep_w<<<3072, 256, 0, stream>>>(w_ih, w_hh, wpre);
  k_prep_cls<<<4096, 256, 0, stream>>>(cls_w, clsp);
  k_prep_gi<<<dim3(64, 128), 256, 0, stream>>>(embp, wpre, b_ih, gi);

  for (int s = 1; s < Td; ++s) {
    const int pPrev = (s - 1) & 1, pCur = s & 1;
    const float* hpf = hbuf + (size_t)pPrev * Bb * Hd;
    float* hnf = hbuf + (size_t)pCur * Bb * Hd;
    const char* hpp = hpre + (size_t)pPrev * 32 * Bb * 128;
    char* hpn = hpre + (size_t)pCur * 32 * Bb * 128;
    k_gates2<<<dim3(64, 2), 256, 0, stream>>>(wpre, gi, hpp,
                                              amax + (size_t)(s - 1) * Bb,
                                              b_hh, hpf, hnf, hpn);
    k_cls2<<<dim3(256, 2), 256, 0, stream>>>(hpn, clsp, cls_b, out,
                                             amax + (size_t)s * Bb, s);
  }
  k_softmax<<<12800, 256, 0, stream>>>(out, amax);
}

// Round 5
// 4322.224 us; speedup vs baseline: 4.1376x; 1.5484x over previous
//
#include <hip/hip_runtime.h>
#include <stdint.h>

// SequenceDecoder: B=128, EMB=512, H=1024, V=8192, T=100 (99 sequential steps).
//  - argmax(log_softmax) == argmax(raw): recurrence needs only raw-logit argmax.
//  - fp16 hi/lo split GEMMs (3 MFMA passes, lo x2048) ~22 mantissa bits.
//  - Weights pre-converted ONCE to fp16 hi|lo tile images, LDS XOR-swizzle
//    (chunk ^= row&7) baked in. K-loop staging = global_load_lds 16B DMA.
//  - gi table: gi = emb @ w_ih.T + b_ih for all 8192 vocab rows precomputed;
//    gates GEMM is h-part only (K=1024), GRU fused in epilogue.
//  - PERSISTENT kernel for all 99 steps. r3's failure (acq_rel barriers ->
//    L2 invalidation -> 52.5MB/step weight refetch) fixed by:
//      * RELAXED system-scope barrier atomics (no buffer_inv ever),
//      * cross-WG data (hpre, amax) written sc0+sc1 (write-through) and read
//        sc0+sc1 (L2 bypass, DMA aux=17) -> no stale copies, no maintenance,
//      * weights stay L2-resident; logits stored nontemporal.
//    256 WGs x 256 thr, 80KB LDS -> 1 WG/CU -> co-residency guaranteed.

#define Bb   128
#define EMBd 512
#define Hd   1024
#define Vd   8192
#define Td   100

typedef __attribute__((ext_vector_type(8))) _Float16 half8;
typedef __attribute__((ext_vector_type(4))) float f32x4;
typedef unsigned long long ull;

#define LOSCALE 2048.0f
#define LOINV   (1.0f/2048.0f)

#define WAITV(N) do { asm volatile("s_waitcnt vmcnt(" #N ")" ::: "memory"); \
                      __builtin_amdgcn_sched_barrier(0); } while (0)
#define WAITL    do { asm volatile("s_waitcnt lgkmcnt(0)" ::: "memory");    \
                      __builtin_amdgcn_sched_barrier(0); } while (0)

__device__ __forceinline__ uint32_t fkey(float f) {
  uint32_t u = __float_as_uint(f);
  return (u & 0x80000000u) ? ~u : (u | 0x80000000u);
}
__device__ __forceinline__ ull umax64(ull a, ull b) { return a > b ? a : b; }

__device__ __forceinline__ void dma16(const void* g, void* l) {
  __builtin_amdgcn_global_load_lds((const uint32_t*)g, (uint32_t*)l, 16, 0, 0);
}
// L2-bypass DMA: aux 17 = SC0|SC1 (system-coherent, fetch from LLC)
__device__ __forceinline__ void dma16s(const void* g, void* l) {
  __builtin_amdgcn_global_load_lds((const uint32_t*)g, (uint32_t*)l, 16, 0, 17);
}
// write-through 16B store (visible at LLC once vmcnt retires)
__device__ __forceinline__ void st16sc(void* p, half8 v) {
  f32x4 d = *(f32x4*)&v;
  asm volatile("global_store_dwordx4 %0, %1, off sc0 sc1"
               :: "v"(p), "v"(d) : "memory");
}
__device__ __forceinline__ ull sysld64(const ull* p) {
  return __hip_atomic_load((ull*)p, __ATOMIC_RELAXED, __HIP_MEMORY_SCOPE_SYSTEM);
}

// split 8 fp32 into fp16 hi + (lo*2048)
__device__ __forceinline__ void cvt8(const float4 v0, const float4 v1,
                                     half8& hh, half8& ll) {
  float vv[8] = {v0.x, v0.y, v0.z, v0.w, v1.x, v1.y, v1.z, v1.w};
#pragma unroll
  for (int i = 0; i < 8; ++i) {
    _Float16 h = (_Float16)vv[i];
    hh[i] = h;
    ll[i] = (_Float16)((vv[i] - (float)h) * LOSCALE);
  }
}

// ---------------------------------------------------------------- init
__global__ void k_init(const float* __restrict__ x, float* __restrict__ hbuf0,
                       ull* __restrict__ amax, char* __restrict__ hpre0,
                       uint32_t* __restrict__ bar) {
  int tid = blockIdx.x * 256 + threadIdx.x;
  if (tid < Bb * Hd) hbuf0[tid] = x[tid];
  if (tid < Td * Bb) amax[tid] = (tid < Bb) ? 0xFFFFFFFFull : 0ull;  // t=0: idx=0
  if (tid >= 16384 && tid < 16384 + 256) bar[tid - 16384] = 0;
  if (tid < 16384) {
    int b = tid & 127, sc = tid >> 7;
    int st = sc >> 2, c = sc & 3;
    const float* src = x + b * Hd + st * 32 + c * 8;
    float4 v0 = *(const float4*)src, v1 = *(const float4*)(src + 4);
    half8 hh, ll; cvt8(v0, v1, hh, ll);
    char* hp = hpre0 + st * 16384 + b * 128;
    *(half8*)(hp + ((c       ^ (b & 7))) * 16) = hh;
    *(half8*)(hp + (((c + 4) ^ (b & 7))) * 16) = ll;
  }
}

// ------------------------------------------------------------- prep kernels
// emb_pre: [row 8192][st_e 16][chunk 8][16B], UNSWIZZLED
__global__ void k_prep_emb(const float* __restrict__ emb, char* __restrict__ embp) {
  int t = blockIdx.x * 256 + threadIdx.x;          // 524288 total
  int row = t >> 6, rem = t & 63, st = rem >> 2, c = rem & 3;
  const float* src = emb + (size_t)row * EMBd + st * 32 + c * 8;
  float4 v0 = *(const float4*)src, v1 = *(const float4*)(src + 4);
  half8 hh, ll; cvt8(v0, v1, hh, ll);
  char* d = embp + (size_t)row * 2048 + st * 128;
  *(half8*)(d + c * 16) = hh;
  *(half8*)(d + (c + 4) * 16) = ll;
}

// wpre: per (cg,q,st) tile: [48 rows][128B], swizzled (chunk ^= r&7)
__global__ void k_prep_w(const float* __restrict__ w_ih, const float* __restrict__ w_hh,
                         char* __restrict__ wpre) {
  int bi = blockIdx.x;                 // (cg*4+q)*12+st, 3072 blocks
  int st = bi % 12, t2 = bi / 12, q = t2 & 3, cg = t2 >> 2;
  int t = threadIdx.x; if (t >= 192) return;
  int r = t >> 2, c = t & 3;
  int g = r >> 4, bn = r & 15;
  int k0 = q * 384 + st * 32 + c * 8;
  const float* src = (k0 < 512)
    ? (w_ih + (size_t)(g * 1024 + cg * 16 + bn) * EMBd + k0)
    : (w_hh + (size_t)(g * 1024 + cg * 16 + bn) * Hd + (k0 - 512));
  float4 v0 = *(const float4*)src, v1 = *(const float4*)(src + 4);
  half8 hh, ll; cvt8(v0, v1, hh, ll);
  char* d = wpre + (size_t)bi * 6144 + r * 128;
  *(half8*)(d + ((c       ^ (r & 7))) * 16) = hh;
  *(half8*)(d + (((c + 4) ^ (r & 7))) * 16) = ll;
}

// clspre: [ct 128][st 32][64 rows][128B], swizzled
__global__ void k_prep_cls(const float* __restrict__ cls_w, char* __restrict__ clsp) {
  int b = blockIdx.x;                  // ct*32+st, 4096 blocks
  int ct = b >> 5, st = b & 31;
  int t = threadIdx.x;
  int r = t >> 2, c = t & 3;
  const float* src = cls_w + (size_t)(ct * 64 + r) * Hd + st * 32 + c * 8;
  float4 v0 = *(const float4*)src, v1 = *(const float4*)(src + 4);
  half8 hh, ll; cvt8(v0, v1, hh, ll);
  char* d = clsp + (size_t)b * 8192 + r * 128;
  *(half8*)(d + ((c       ^ (r & 7))) * 16) = hh;
  *(half8*)(d + (((c + 4) ^ (r & 7))) * 16) = ll;
}

// ------------------------------------------- gi table: emb @ w_ih.T + b_ih
__global__ __launch_bounds__(256, 2) void k_prep_gi(
    const char* __restrict__ embp, const char* __restrict__ wpre,
    const float* __restrict__ b_ih, float* __restrict__ gi)
{
  const int cg = blockIdx.x, vh = blockIdx.y;
  const int tid = threadIdx.x, lane = tid & 63, w = tid >> 6;
  const int C = cg * 16;
  __shared__ __align__(16) char pA[4 * 8192];
  __shared__ __align__(16) char pB[4 * 6144];

  f32x4 accH[3], accL[3];
#pragma unroll
  for (int g = 0; g < 3; ++g) {
    accH[g] = (f32x4){0.f, 0.f, 0.f, 0.f};
    accL[g] = (f32x4){0.f, 0.f, 0.f, 0.f};
  }

  const int rr = lane >> 3, cc = lane & 7;
  const char* abase = embp + (size_t)(vh * 64 + w * 16 + rr) * 2048 + ((cc ^ rr) * 16);

  auto issue = [&](int st) {
    char* da = pA + (st & 3) * 8192 + w * 2048;
    const char* s0 = abase + st * 128;
    dma16(s0, da);
    dma16(s0 + 8 * 2048, da + 1024);
    const int wq = st / 12, wst = st - wq * 12;
    const char* sb = wpre + (size_t)((cg * 4 + wq) * 12 + wst) * 6144 + w * 1536 + lane * 16;
    char* db = pB + (st & 3) * 6144 + w * 1536;
    dma16(sb, db);
    if (lane < 32) dma16(sb + 1024, db + 1024);
  };

  const int l15 = lane & 15, qd = lane >> 4, r7 = l15 & 7;
  const int offAH = (w * 16 + l15) * 128 + ((qd)     ^ r7) * 16;
  const int offAL = (w * 16 + l15) * 128 + ((qd + 4) ^ r7) * 16;

  issue(0); issue(1); issue(2);
  WAITV(8);
  __builtin_amdgcn_s_barrier();

  for (int st = 0; st < 16; ++st) {
    const int bf = st & 3;
    half8 aH = *(half8*)&pA[bf * 8192 + offAH];
    half8 aL = *(half8*)&pA[bf * 8192 + offAL];
    if (st + 3 < 16) issue(st + 3);
#pragma unroll
    for (int g = 0; g < 3; ++g) {
      half8 bH = *(half8*)&pB[bf * 6144 + (g * 16 + l15) * 128 + ((qd)     ^ r7) * 16];
      half8 bL = *(half8*)&pB[bf * 6144 + (g * 16 + l15) * 128 + ((qd + 4) ^ r7) * 16];
      accH[g] = __builtin_amdgcn_mfma_f32_16x16x32_f16(aH, bH, accH[g], 0, 0, 0);
      accL[g] = __builtin_amdgcn_mfma_f32_16x16x32_f16(aH, bL, accL[g], 0, 0, 0);
      accL[g] = __builtin_amdgcn_mfma_f32_16x16x32_f16(aL, bH, accL[g], 0, 0, 0);
    }
    if (st < 15) {
      if (st <= 12)      { WAITV(8); }
      else if (st == 13) { WAITV(4); }
      else               { WAITV(0); }
      WAITL;
      __builtin_amdgcn_s_barrier();
    }
  }

  const int v0 = vh * 64 + w * 16 + qd * 4;
#pragma unroll
  for (int g = 0; g < 3; ++g) {
    float bi = b_ih[g * 1024 + C + l15];
#pragma unroll
    for (int i = 0; i < 4; ++i) {
      float val = accH[g][i] + accL[g][i] * LOINV + bi;
      gi[(size_t)(v0 + i) * 3072 + g * 1024 + C + l15] = val;
    }
  }
}

// ---------------------------------------------------------- grid barrier
// RELAXED two-level barrier: 8 group counters -> root. NO acq/rel (no cache
// maintenance). Ordering: __syncthreads drains vmcnt (sc-stores visible)
// before tid0 signals; consumers read barriered data via sc0sc1 bypass.
__device__ __forceinline__ void relbar(uint32_t* __restrict__ bar, int wg, uint32_t gen) {
  __syncthreads();
  if (threadIdx.x == 0) {
    const int g = wg & 7;
    uint32_t old = __hip_atomic_fetch_add(&bar[g * 16], 1u, __ATOMIC_RELAXED,
                                          __HIP_MEMORY_SCOPE_SYSTEM);
    if (old + 1u == gen * 32u)
      __hip_atomic_fetch_add(&bar[128], 1u, __ATOMIC_RELAXED,
                             __HIP_MEMORY_SCOPE_SYSTEM);
    while (__hip_atomic_load(&bar[128], __ATOMIC_RELAXED,
                             __HIP_MEMORY_SCOPE_SYSTEM) < gen * 8u)
      __builtin_amdgcn_s_sleep(4);
  }
  __syncthreads();
}

// ----------------------------------------------- persistent full-loop kernel
__global__ __launch_bounds__(256) void k_loop(
    const char* __restrict__ wpre, const char* __restrict__ clsp,
    const float* __restrict__ gi,
    const float* __restrict__ b_hh, const float* __restrict__ cls_b,
    float* __restrict__ hbuf, char* __restrict__ hpre,
    ull* __restrict__ amax, float* __restrict__ out,
    uint32_t* __restrict__ bar)
{
  const int wg = blockIdx.x;
  const int tid = threadIdx.x, lane = tid & 63, w = tid >> 6;
  __shared__ __align__(16) char smem[81920];   // 80KB -> 1 WG/CU guaranteed

  const int l15 = lane & 15, qd = lane >> 4, r7 = l15 & 7;

  // gates role (wg < 128): cg = wg&63, rh = bit6
  const int cg = wg & 63, rh = (wg >> 6) & 1;
  const int C = cg * 16;
  // cls role (all): ct = wg&127, rt0 = bit7
  const int ct = wg & 127, rt0 = wg >> 7;
  const int r0c = rt0 * 64, c0c = ct * 64;
  const char* c_bsrc = clsp + (size_t)ct * 262144 + w * 2048 + lane * 16;

  const int offA_H = (w * 16 + l15) * 128 + ((qd)     ^ r7) * 16;
  const int offA_L = (w * 16 + l15) * 128 + ((qd + 4) ^ r7) * 16;

  uint32_t gen = 0;

  for (int s = 1; s < Td; ++s) {
    const int pPrev = (s - 1) & 1, pCur = s & 1;

    // ================== gates GEMM (h-part, K=1024) + fused GRU ==========
    if (wg < 128) {
      const ull* amax_prev = amax + (size_t)(s - 1) * Bb;
      const char* hsrc = hpre + (size_t)pPrev * 32 * Bb * 128
                         + rh * 8192 + w * 2048 + lane * 16;   // +st*16384
      char* gA = smem;               // 4 * 8192
      char* gB = smem + 32768;       // 4 * 6144

      f32x4 accH[3], accL[3];
#pragma unroll
      for (int g = 0; g < 3; ++g) {
        accH[g] = (f32x4){0.f, 0.f, 0.f, 0.f};
        accL[g] = (f32x4){0.f, 0.f, 0.f, 0.f};
      }

      auto issue = [&](int st) {
        char* da = gA + (st & 3) * 8192 + w * 2048;
        const char* sa = hsrc + st * 16384;
        dma16s(sa, da);                    // hpre: cross-WG -> L2 bypass
        dma16s(sa + 1024, da + 1024);
        const int k0 = 512 + st * 32;
        const int wq = (k0 >= 1152) ? 3 : (k0 >= 768 ? 2 : 1);
        const int wst = (k0 - wq * 384) >> 5;
        const char* sb = wpre + (size_t)((cg * 4 + wq) * 12 + wst) * 6144 + w * 1536 + lane * 16;
        char* db = gB + (st & 3) * 6144 + w * 1536;
        dma16(sb, db);                     // weights: normal cached
        if (lane < 32) dma16(sb + 1024, db + 1024);
      };

      issue(0); issue(1); issue(2);
      WAITV(8);
      __builtin_amdgcn_s_barrier();

      for (int st = 0; st < 32; ++st) {
        const int bf = st & 3;
        half8 aH = *(half8*)&gA[bf * 8192 + offA_H];
        half8 aL = *(half8*)&gA[bf * 8192 + offA_L];
        if (st + 3 < 32) issue(st + 3);
#pragma unroll
        for (int g = 0; g < 3; ++g) {
          half8 bH = *(half8*)&gB[bf * 6144 + (g * 16 + l15) * 128 + ((qd)     ^ r7) * 16];
          half8 bL = *(half8*)&gB[bf * 6144 + (g * 16 + l15) * 128 + ((qd + 4) ^ r7) * 16];
          accH[g] = __builtin_amdgcn_mfma_f32_16x16x32_f16(aH, bH, accH[g], 0, 0, 0);
          accL[g] = __builtin_amdgcn_mfma_f32_16x16x32_f16(aH, bL, accL[g], 0, 0, 0);
          accL[g] = __builtin_amdgcn_mfma_f32_16x16x32_f16(aL, bH, accL[g], 0, 0, 0);
        }
        if (st < 31) {
          if (st <= 28)      { WAITV(8); }
          else if (st == 29) { WAITV(4); }
          else               { WAITV(0); }
          WAITL;
          __builtin_amdgcn_s_barrier();
        }
      }

      // GRU epilogue: 4 rows x 1 col per lane
      const int j = C + l15;
      const float bh0 = b_hh[j], bh1 = b_hh[1024 + j], bh2 = b_hh[2048 + j];
      const float* hprev_f = hbuf + (size_t)pPrev * Bb * Hd;
      float* hnew_f = hbuf + (size_t)pCur * Bb * Hd;
      float outs[4];
#pragma unroll
      for (int i = 0; i < 4; ++i) {
        const int ri = rh * 64 + w * 16 + qd * 4 + i;
        const uint32_t idx = (~(uint32_t)sysld64(&amax_prev[ri])) & 8191u;
        const float* gp = gi + (size_t)idx * 3072 + j;
        float i_r = gp[0], i_z = gp[1024], i_n = gp[2048];
        float h_r = accH[0][i] + accL[0][i] * LOINV + bh0;
        float h_z = accH[1][i] + accL[1][i] * LOINV + bh1;
        float h_n = accH[2][i] + accL[2][i] * LOINV + bh2;
        float rr2 = 1.f / (1.f + expf(-(i_r + h_r)));
        float zz = 1.f / (1.f + expf(-(i_z + h_z)));
        float nn = tanhf(i_n + rr2 * h_n);
        float o = (1.f - zz) * nn + zz * hprev_f[ri * Hd + j];
        hnew_f[ri * Hd + j] = o;          // WG-private slice (persistent WG)
        outs[i] = o;
      }
      // transpose via LDS -> 16B write-through hpre stores
      __syncthreads();
      float* sT = (float*)smem;
#pragma unroll
      for (int i = 0; i < 4; ++i)
        sT[(w * 16 + qd * 4 + i) * 16 + l15] = outs[i];
      __syncthreads();
      if (tid < 128) {
        const int row = tid >> 1, half = tid & 1;
        const int b = rh * 64 + row;
        const float* srcp = sT + row * 16 + half * 8;
        half8 hh, ll;
#pragma unroll
        for (int e = 0; e < 8; ++e) {
          float o = srcp[e];
          _Float16 oh = (_Float16)o;
          hh[e] = oh;
          ll[e] = (_Float16)((o - (float)oh) * LOSCALE);
        }
        const int stp = C >> 5;
        const int chb = ((C & 31) >> 3) + half;
        char* hp = hpre + (size_t)pCur * 32 * Bb * 128 + stp * 16384 + b * 128;
        st16sc(hp + ((chb       ^ (b & 7))) * 16, hh);
        st16sc(hp + (((chb + 4) ^ (b & 7))) * 16, ll);
      }
    }

    ++gen; relbar(bar, wg, gen);   // h tiles (sc-written) + done

    // ======================= cls GEMM + argmax =======================
    {
      const char* asrc = hpre + (size_t)pCur * 32 * Bb * 128
                         + rt0 * 8192 + w * 2048 + lane * 16;   // +st*16384
      char* cA = smem;               // 4 * 8192
      char* cB = smem + 32768;       // 4 * 8192

      f32x4 accH[4], accL[4];
#pragma unroll
      for (int i = 0; i < 4; ++i) {
        accH[i] = (f32x4){0.f, 0.f, 0.f, 0.f};
        accL[i] = (f32x4){0.f, 0.f, 0.f, 0.f};
      }

      auto issue = [&](int st) {
        char* da = cA + (st & 3) * 8192 + w * 2048;
        const char* sa = asrc + st * 16384;
        dma16s(sa, da);                    // hpre: bypass
        dma16s(sa + 1024, da + 1024);
        char* db = cB + (st & 3) * 8192 + w * 2048;
        const char* sb = c_bsrc + st * 8192;
        dma16(sb, db);                     // weights: cached
        dma16(sb + 1024, db + 1024);
      };

      issue(0); issue(1); issue(2);
      WAITV(8);
      __builtin_amdgcn_s_barrier();

      for (int st = 0; st < 32; ++st) {
        const int bf = st & 3;
        half8 aH = *(half8*)&cA[bf * 8192 + offA_H];
        half8 aL = *(half8*)&cA[bf * 8192 + offA_L];
        if (st + 3 < 32) issue(st + 3);
#pragma unroll
        for (int cf = 0; cf < 4; ++cf) {
          half8 bH = *(half8*)&cB[bf * 8192 + (cf * 16 + l15) * 128 + ((qd)     ^ r7) * 16];
          half8 bL = *(half8*)&cB[bf * 8192 + (cf * 16 + l15) * 128 + ((qd + 4) ^ r7) * 16];
          accH[cf] = __builtin_amdgcn_mfma_f32_16x16x32_f16(aH, bH, accH[cf], 0, 0, 0);
          accL[cf] = __builtin_amdgcn_mfma_f32_16x16x32_f16(aH, bL, accL[cf], 0, 0, 0);
          accL[cf] = __builtin_amdgcn_mfma_f32_16x16x32_f16(aL, bH, accL[cf], 0, 0, 0);
        }
        if (st < 31) {
          if (st <= 28)      { WAITV(8); }
          else if (st == 29) { WAITV(4); }
          else               { WAITV(0); }
          WAITL;
          __builtin_amdgcn_s_barrier();
        }
      }

      // epilogue: +bias, nontemporal logit stores, packed argmax atomicMax
      float bsv[4];
#pragma unroll
      for (int cf = 0; cf < 4; ++cf) bsv[cf] = cls_b[c0c + cf * 16 + l15];
#pragma unroll
      for (int i = 0; i < 4; ++i) {
        const int brow = r0c + w * 16 + qd * 4 + i;
        float* orow = out + ((size_t)brow * Td + s) * Vd;
        ull best = 0ull;
#pragma unroll
        for (int cf = 0; cf < 4; ++cf) {
          const int v = c0c + cf * 16 + l15;
          float val = accH[cf][i] + accL[cf][i] * LOINV + bsv[cf];
          __builtin_nontemporal_store(val, &orow[v]);
          best = umax64(best, ((ull)fkey(val) << 32) | (uint32_t)(~(uint32_t)v));
        }
        best = umax64(best, __shfl_xor(best, 1));
        best = umax64(best, __shfl_xor(best, 2));
        best = umax64(best, __shfl_xor(best, 4));
        best = umax64(best, __shfl_xor(best, 8));
        if (l15 == 0) atomicMax(&amax[(size_t)s * Bb + brow], best);
      }
    }

    ++gen; relbar(bar, wg, gen);   // amax done for next step's gather
  }
}

// -------------------------------------------------- final log_softmax pass
__global__ void k_softmax(float* __restrict__ out,
                          const ull* __restrict__ amax) {
  int blk = blockIdx.x;           // 12800 = 128*100
  int t = blk % Td, b = blk / Td;
  int tid = threadIdx.x;
  float* row = out + ((size_t)b * Td + t) * Vd;
  if (t == 0) {
    float lse0 = logf(expf(1.0f) + (float)(Vd - 1));
    for (int i = tid; i < Vd; i += 256) row[i] = ((i == 0) ? 1.0f : 0.0f) - lse0;
    return;
  }
  ull key = amax[t * Bb + b];
  uint32_t ku = (uint32_t)(key >> 32);
  uint32_t u = (ku & 0x80000000u) ? (ku & 0x7fffffffu) : ~ku;
  float m = __uint_as_float(u);
  float x[32];
  float ssum = 0.f;
#pragma unroll
  for (int i = 0; i < 32; ++i) {
    x[i] = row[tid + i * 256];
    ssum += expf(x[i] - m);
  }
  ssum += __shfl_xor(ssum, 1);
  ssum += __shfl_xor(ssum, 2);
  ssum += __shfl_xor(ssum, 4);
  ssum += __shfl_xor(ssum, 8);
  ssum += __shfl_xor(ssum, 16);
  ssum += __shfl_xor(ssum, 32);
  __shared__ float wsum[4];
  if ((tid & 63) == 0) wsum[tid >> 6] = ssum;
  __syncthreads();
  float lse = m + logf(wsum[0] + wsum[1] + wsum[2] + wsum[3]);
#pragma unroll
  for (int i = 0; i < 32; ++i) row[tid + i * 256] = x[i] - lse;
}

// ----------------------------------------------------------------- launch
extern "C" void kernel_launch(void* const* d_in, const int* in_sizes, int n_in,
                              void* d_out, int out_size, void* d_ws, size_t ws_size,
                              hipStream_t stream) {
  const float* x     = (const float*)d_in[0];
  const float* emb   = (const float*)d_in[1];
  const float* w_ih  = (const float*)d_in[2];
  const float* w_hh  = (const float*)d_in[3];
  const float* b_ih  = (const float*)d_in[4];
  const float* b_hh  = (const float*)d_in[5];
  const float* cls_w = (const float*)d_in[6];
  const float* cls_b = (const float*)d_in[7];
  float* out = (float*)d_out;

  char* ws = (char*)d_ws;
  size_t o = 0;
  ull*      amax = (ull*)(ws + o);      o += (size_t)Td * Bb * 8;      // 100 KB
  uint32_t* bar  = (uint32_t*)(ws + o); o += 1024;
  float*    hbuf = (float*)(ws + o);    o += (size_t)2 * Bb * Hd * 4;  // 1 MB
  char*     hpre = ws + o;              o += (size_t)2 * 32 * Bb * 128; // 1 MB
  char*     embp = ws + o;              o += (size_t)Vd * 2048;        // 16.8 MB
  char*     wpre = ws + o;              o += (size_t)3072 * 6144;      // 18.9 MB
  char*     clsp = ws + o;              o += (size_t)128 * 32 * 8192;  // 33.6 MB
  float*    gi   = (float*)(ws + o);    o += (size_t)Vd * 3072 * 4;    // 100.7 MB

  k_init<<<512, 256, 0, stream>>>(x, hbuf, amax, hpre, bar);
  k_prep_emb<<<2048, 256, 0, stream>>>(emb, embp);
  k_prep_w<<<3072, 256, 0, stream>>>(w_ih, w_hh, wpre);
  k_prep_cls<<<4096, 256, 0, stream>>>(cls_w, clsp);
  k_prep_gi<<<dim3(64, 128), 256, 0, stream>>>(embp, wpre, b_ih, gi);

  k_loop<<<256, 256, 0, stream>>>(wpre, clsp, gi, b_hh, cls_b,
                                  hbuf, hpre, amax, out, bar);

  k_softmax<<<12800, 256, 0, stream>>>(out, amax);
}